// Round 1
// baseline (330.775 us; speedup 1.0000x reference)
//
#include <hip/hip_runtime.h>
#include <hip/hip_bf16.h>
#include <cstdint>

#define M_ROWS 131072
#define D_DIM  256
#define K_CL   512

typedef __attribute__((ext_vector_type(4))) float  f4;
typedef __attribute__((ext_vector_type(8))) short  bfrag;   // 8 bf16 (4 VGPRs)
typedef __attribute__((ext_vector_type(4))) float  ffrag;   // 4 f32 acc

#define MFMA16(A,B,C) __builtin_amdgcn_mfma_f32_16x16x32_bf16((A),(B),(C),0,0,0)

__device__ __forceinline__ unsigned short f2bf(float f) {
    unsigned int u = __float_as_uint(f);
    u += 0x7FFFu + ((u >> 16) & 1u);          // round-to-nearest-even
    return (unsigned short)(u >> 16);
}
__device__ __forceinline__ float bf2f(unsigned short u) {
    return __uint_as_float(((unsigned int)u) << 16);
}

// ---------------------------------------------------------------------------
// Prep: cluster_center f32 [512][256] -> Cb bf16 [512][256], Ct bf16 [256][512],
// c_sq[512] (sum of squares of the bf16-rounded values, f32 accum).
// ---------------------------------------------------------------------------
__global__ void prep_kernel(const float* __restrict__ C,
                            unsigned short* __restrict__ Cb,
                            unsigned short* __restrict__ Ct,
                            float* __restrict__ csq)
{
    __shared__ unsigned short lds[64 * 264];
    const int tid = threadIdx.x;          // 256 threads
    const int kb  = blockIdx.x * 64;      // 8 blocks
    const int r   = tid >> 2;             // local k row 0..63
    const int q   = tid & 3;              // 4 threads per row

    const float* cr = C + (size_t)(kb + r) * D_DIM;
    float s = 0.f;
    #pragma unroll
    for (int i = 0; i < 16; ++i) {
        const int j = q * 16 + i;         // float4 index 0..63
        f4 v = *(const f4*)(cr + j * 4);
        unsigned short u0 = f2bf(v[0]), u1 = f2bf(v[1]), u2 = f2bf(v[2]), u3 = f2bf(v[3]);
        *(ushort4*)(Cb + (size_t)(kb + r) * D_DIM + j * 4) = make_ushort4(u0, u1, u2, u3);
        *(ushort4*)(lds + r * 264 + j * 4)                  = make_ushort4(u0, u1, u2, u3);
        float f0 = bf2f(u0), f1 = bf2f(u1), f2_ = bf2f(u2), f3 = bf2f(u3);
        s += f0 * f0 + f1 * f1 + f2_ * f2_ + f3 * f3;
    }
    s += __shfl_xor(s, 1, 64);
    s += __shfl_xor(s, 2, 64);
    if (q == 0) csq[kb + r] = s;
    __syncthreads();

    // transposed copy: thread tid = d (0..255), contiguous 64 k's
    #pragma unroll
    for (int c = 0; c < 16; ++c) {
        ushort4 p = make_ushort4(lds[(c * 4 + 0) * 264 + tid],
                                 lds[(c * 4 + 1) * 264 + tid],
                                 lds[(c * 4 + 2) * 264 + tid],
                                 lds[(c * 4 + 3) * 264 + tid]);
        *(ushort4*)(Ct + (size_t)tid * K_CL + kb + c * 4) = p;
    }
}

// ---------------------------------------------------------------------------
// Fused: LayerNorm -> cdist (GEMM1) -> NegSoftAssign softmax -> x_rec (GEMM2)
// Block: 256 threads (4 waves), 32 rows. Waves split K=512 into 4x128 (GEMM1)
// and D=256 into 4x64 (GEMM2).
// ---------------------------------------------------------------------------
__global__ __launch_bounds__(256)
void fused_kernel(const float* __restrict__ x,
                  const float* __restrict__ lnw,
                  const float* __restrict__ lnb,
                  const unsigned short* __restrict__ Cb,
                  const unsigned short* __restrict__ Ct,
                  const float* __restrict__ csq,
                  float* __restrict__ out0,   // x_distance  [M][512]
                  float* __restrict__ out1,   // assign      [M][512]
                  float* __restrict__ out2)   // x_rec       [M][256]
{
    __shared__ __align__(16) char smem[51712];
    unsigned short* xn_s = (unsigned short*)smem;             // [32][264] bf16 (pad 8)
    unsigned short* as_s = (unsigned short*)(smem + 16896);   // [32][520] bf16 (pad 8)
    float* csq_s = (float*)(smem + 16896);                    // [512]  (union with as_s)
    float* red_a = (float*)(smem + 50176);                    // [128]
    float* red_b = (float*)(smem + 50688);                    // [128]
    float* xsq_s = (float*)(smem + 51200);                    // [32]
    float* sc_s  = (float*)(smem + 51328);                    // [32] 32/mean_d
    float* mn_s  = (float*)(smem + 51456);                    // [32] min_d
    float* rn_s  = (float*)(smem + 51584);                    // [32] 1/sumexp

    const int tid = threadIdx.x;
    const int w   = tid >> 6;        // wave 0..3
    const int l   = tid & 63;
    const int g   = l >> 4;          // 16-lane group
    const int cl  = l & 15;
    const int m0  = blockIdx.x * 32;

    // stage c_sq into LDS (union region: only valid until phase D2 overwrites)
    csq_s[tid]       = csq[tid];
    csq_s[tid + 256] = csq[tid + 256];

    // ---- Phase A: LayerNorm (8 lanes per row) ----
    {
        const int row = tid >> 3, sub = tid & 7;
        const float* xr = x + (size_t)(m0 + row) * D_DIM;
        f4 xv[8];
        float sum = 0.f, ss = 0.f;
        #pragma unroll
        for (int i = 0; i < 8; ++i) {
            xv[i] = *(const f4*)(xr + (i * 8 + sub) * 4);
            #pragma unroll
            for (int c = 0; c < 4; ++c) { float v = xv[i][c]; sum += v; ss += v * v; }
        }
        #pragma unroll
        for (int msk = 1; msk < 8; msk <<= 1) {
            sum += __shfl_xor(sum, msk, 64);
            ss  += __shfl_xor(ss,  msk, 64);
        }
        const float mean = sum * (1.0f / 256.0f);
        float var = ss * (1.0f / 256.0f) - mean * mean;
        var = fmaxf(var, 0.0f);
        const float inv = 1.0f / (sqrtf(var) + 1e-5f);

        float xsq = 0.f;
        #pragma unroll
        for (int i = 0; i < 8; ++i) {
            f4 wv = *(const f4*)(lnw + (i * 8 + sub) * 4);
            f4 bv = *(const f4*)(lnb + (i * 8 + sub) * 4);
            unsigned short u0, u1, u2, u3;
            {
                float a0 = (xv[i][0] - mean) * inv * wv[0] + bv[0];
                float a1 = (xv[i][1] - mean) * inv * wv[1] + bv[1];
                float a2 = (xv[i][2] - mean) * inv * wv[2] + bv[2];
                float a3 = (xv[i][3] - mean) * inv * wv[3] + bv[3];
                u0 = f2bf(a0); u1 = f2bf(a1); u2 = f2bf(a2); u3 = f2bf(a3);
                float b0 = bf2f(u0), b1 = bf2f(u1), b2 = bf2f(u2), b3 = bf2f(u3);
                xsq += b0 * b0 + b1 * b1 + b2 * b2 + b3 * b3;
            }
            *(ushort4*)(xn_s + row * 264 + (i * 8 + sub) * 4) = make_ushort4(u0, u1, u2, u3);
        }
        #pragma unroll
        for (int msk = 1; msk < 8; msk <<= 1) xsq += __shfl_xor(xsq, msk, 64);
        if (sub == 0) xsq_s[row] = xsq;
    }
    __syncthreads();

    // ---- Phase A2: GEMM1  S = xn @ C^T  (wave covers cols nb..nb+127) ----
    const int nb = w * 128;
    ffrag acc[2][8];
    #pragma unroll
    for (int rt = 0; rt < 2; ++rt)
        #pragma unroll
        for (int nt = 0; nt < 8; ++nt)
            acc[rt][nt] = (ffrag){0.f, 0.f, 0.f, 0.f};
    {
        bfrag a[2][8];
        #pragma unroll
        for (int rt = 0; rt < 2; ++rt)
            #pragma unroll
            for (int ks = 0; ks < 8; ++ks)
                a[rt][ks] = *(const bfrag*)(xn_s + (rt * 16 + cl) * 264 + ks * 32 + g * 8);
        #pragma unroll
        for (int nt = 0; nt < 8; ++nt) {
            const unsigned short* bp = Cb + (size_t)(nb + nt * 16 + cl) * D_DIM + g * 8;
            #pragma unroll
            for (int ks = 0; ks < 8; ++ks) {
                bfrag b = *(const bfrag*)(bp + ks * 32);
                acc[0][nt] = MFMA16(a[0][ks], b, acc[0][nt]);
                acc[1][nt] = MFMA16(a[1][ks], b, acc[1][nt]);
            }
        }
    }

    // ---- Phase B: distances + store out0 ----
    float xsq_r[2][4];
    #pragma unroll
    for (int rt = 0; rt < 2; ++rt)
        #pragma unroll
        for (int r = 0; r < 4; ++r)
            xsq_r[rt][r] = xsq_s[rt * 16 + g * 4 + r];

    #pragma unroll
    for (int nt = 0; nt < 8; ++nt) {
        const float cs = csq_s[nb + nt * 16 + cl];
        #pragma unroll
        for (int rt = 0; rt < 2; ++rt)
            #pragma unroll
            for (int r = 0; r < 4; ++r) {
                float d2 = xsq_r[rt][r] + cs - 2.0f * acc[rt][nt][r];
                float d  = sqrtf(fmaxf(d2, 0.0f));
                acc[rt][nt][r] = d;
                out0[(size_t)(m0 + rt * 16 + g * 4 + r) * K_CL + nb + nt * 16 + cl] = d;
            }
    }

    // ---- Phase C: row sum & min (wave-local then cross-wave) ----
    {
        float s[2][4], mn[2][4];
        #pragma unroll
        for (int rt = 0; rt < 2; ++rt)
            #pragma unroll
            for (int r = 0; r < 4; ++r) { s[rt][r] = acc[rt][0][r]; mn[rt][r] = acc[rt][0][r]; }
        #pragma unroll
        for (int nt = 1; nt < 8; ++nt)
            #pragma unroll
            for (int rt = 0; rt < 2; ++rt)
                #pragma unroll
                for (int r = 0; r < 4; ++r) {
                    s[rt][r]  += acc[rt][nt][r];
                    mn[rt][r]  = fminf(mn[rt][r], acc[rt][nt][r]);
                }
        #pragma unroll
        for (int msk = 1; msk < 16; msk <<= 1)
            #pragma unroll
            for (int rt = 0; rt < 2; ++rt)
                #pragma unroll
                for (int r = 0; r < 4; ++r) {
                    s[rt][r]  += __shfl_xor(s[rt][r],  msk, 64);
                    mn[rt][r]  = fminf(mn[rt][r], __shfl_xor(mn[rt][r], msk, 64));
                }
        if (cl == 0) {
            #pragma unroll
            for (int rt = 0; rt < 2; ++rt)
                #pragma unroll
                for (int r = 0; r < 4; ++r) {
                    red_a[w * 32 + rt * 16 + g * 4 + r] = s[rt][r];
                    red_b[w * 32 + rt * 16 + g * 4 + r] = mn[rt][r];
                }
        }
    }
    __syncthreads();
    if (tid < 32) {
        float t0 = red_a[tid] + red_a[32 + tid] + red_a[64 + tid] + red_a[96 + tid];
        float mv = fminf(fminf(red_b[tid], red_b[32 + tid]),
                         fminf(red_b[64 + tid], red_b[96 + tid]));
        sc_s[tid] = 16384.0f / t0;   // 32 / mean_d  (= 32*512/sum)
        mn_s[tid] = mv;
    }
    __syncthreads();

    // ---- Phase D: exp + sumexp ----
    {
        float sc_r[2][4], mnr[2][4], es[2][4];
        #pragma unroll
        for (int rt = 0; rt < 2; ++rt)
            #pragma unroll
            for (int r = 0; r < 4; ++r) {
                sc_r[rt][r] = sc_s[rt * 16 + g * 4 + r];
                mnr[rt][r]  = mn_s[rt * 16 + g * 4 + r];
                es[rt][r]   = 0.f;
            }
        #pragma unroll
        for (int nt = 0; nt < 8; ++nt)
            #pragma unroll
            for (int rt = 0; rt < 2; ++rt)
                #pragma unroll
                for (int r = 0; r < 4; ++r) {
                    float p = __expf((mnr[rt][r] - acc[rt][nt][r]) * sc_r[rt][r]);
                    acc[rt][nt][r] = p;
                    es[rt][r] += p;
                }
        #pragma unroll
        for (int msk = 1; msk < 16; msk <<= 1)
            #pragma unroll
            for (int rt = 0; rt < 2; ++rt)
                #pragma unroll
                for (int r = 0; r < 4; ++r)
                    es[rt][r] += __shfl_xor(es[rt][r], msk, 64);
        if (cl == 0) {
            #pragma unroll
            for (int rt = 0; rt < 2; ++rt)
                #pragma unroll
                for (int r = 0; r < 4; ++r)
                    red_a[w * 32 + rt * 16 + g * 4 + r] = es[rt][r];
        }
    }
    __syncthreads();
    if (tid < 32)
        rn_s[tid] = 1.0f / (red_a[tid] + red_a[32 + tid] + red_a[64 + tid] + red_a[96 + tid]);
    __syncthreads();

    // ---- Phase D2: assign = p * rnorm; store out1 + bf16 into LDS ----
    {
        float rn_r[2][4];
        #pragma unroll
        for (int rt = 0; rt < 2; ++rt)
            #pragma unroll
            for (int r = 0; r < 4; ++r)
                rn_r[rt][r] = rn_s[rt * 16 + g * 4 + r];
        #pragma unroll
        for (int nt = 0; nt < 8; ++nt)
            #pragma unroll
            for (int rt = 0; rt < 2; ++rt)
                #pragma unroll
                for (int r = 0; r < 4; ++r) {
                    float av = acc[rt][nt][r] * rn_r[rt][r];
                    out1[(size_t)(m0 + rt * 16 + g * 4 + r) * K_CL + nb + nt * 16 + cl] = av;
                    as_s[(rt * 16 + g * 4 + r) * 520 + nb + nt * 16 + cl] = f2bf(av);
                }
    }
    __syncthreads();

    // ---- Phase E: GEMM2  x_rec = assign @ C  (wave covers d-cols db..db+63) ----
    {
        ffrag acc2[2][4];
        #pragma unroll
        for (int rt = 0; rt < 2; ++rt)
            #pragma unroll
            for (int nt = 0; nt < 4; ++nt)
                acc2[rt][nt] = (ffrag){0.f, 0.f, 0.f, 0.f};
        const int db = w * 64;
        #pragma unroll
        for (int kt = 0; kt < 16; ++kt) {
            bfrag a0 = *(const bfrag*)(as_s + (cl)      * 520 + kt * 32 + g * 8);
            bfrag a1 = *(const bfrag*)(as_s + (16 + cl) * 520 + kt * 32 + g * 8);
            #pragma unroll
            for (int nt = 0; nt < 4; ++nt) {
                bfrag b = *(const bfrag*)(Ct + (size_t)(db + nt * 16 + cl) * K_CL + kt * 32 + g * 8);
                acc2[0][nt] = MFMA16(a0, b, acc2[0][nt]);
                acc2[1][nt] = MFMA16(a1, b, acc2[1][nt]);
            }
        }
        #pragma unroll
        for (int rt = 0; rt < 2; ++rt)
            #pragma unroll
            for (int nt = 0; nt < 4; ++nt)
                #pragma unroll
                for (int r = 0; r < 4; ++r)
                    out2[(size_t)(m0 + rt * 16 + g * 4 + r) * D_DIM + db + nt * 16 + cl]
                        = acc2[rt][nt][r];
    }
}

extern "C" void kernel_launch(void* const* d_in, const int* in_sizes, int n_in,
                              void* d_out, int out_size, void* d_ws, size_t ws_size,
                              hipStream_t stream)
{
    const float* x   = (const float*)d_in[0];
    const float* lnw = (const float*)d_in[1];
    const float* lnb = (const float*)d_in[2];
    const float* C   = (const float*)d_in[3];

    float* out0 = (float*)d_out;
    float* out1 = out0 + (size_t)M_ROWS * K_CL;
    float* out2 = out1 + (size_t)M_ROWS * K_CL;

    unsigned short* Cb = (unsigned short*)d_ws;                       // 512*256 bf16
    unsigned short* Ct = Cb + (size_t)K_CL * D_DIM;                   // 256*512 bf16
    float*          cs = (float*)((char*)d_ws + 2u * K_CL * D_DIM * 2u); // [512] f32

    prep_kernel<<<8, 256, 0, stream>>>(C, Cb, Ct, cs);
    fused_kernel<<<M_ROWS / 32, 256, 0, stream>>>(x, lnw, lnb, Cb, Ct, cs,
                                                  out0, out1, out2);
}